// Round 4
// baseline (29681.140 us; speedup 1.0000x reference)
//
#include <hip/hip_runtime.h>

#define NB    256
#define BT    1024
#define BATCH 128
#define HID   512
#define XSZ   64
#define SSZ   16
#define PAD   32          // ints per flag slot = 128B
#define SPIN_MAX (1 << 18)

typedef unsigned int uint;
typedef _Float16 half2v __attribute__((ext_vector_type(2)));

// ---------------- persistent device state ----------------
__device__ __align__(16) uint  g_h0P[2][256 * 128];   // f16 pairs (col 2m lo, 2m+1 hi) x 128 batch
__device__ __align__(16) uint  g_h1P[2][256 * 128];
__device__ __align__(16) uint  g_h1Nh[128 * 256];     // row-major per batch: [b][m] f16 pairs (fc path)
__device__ __align__(16) float g_Wcomb[4 * HID * HID];// 0.1 * W0s @ Wfc  [2048][512] fp32
__device__ int g_flags[NB * PAD];

// ---------------- helpers ----------------
__device__ __forceinline__ float sigf(float x) { return 1.f / (1.f + __expf(-x)); }
__device__ __forceinline__ float tanh_fast(float x) {
  float ax = fabsf(x); float e = __expf(-2.f * ax);
  return copysignf((1.f - e) / (1.f + e), x);
}
__device__ __forceinline__ uint pack_f16(float a, float b) {
  half2v h; h.x = (_Float16)a; h.y = (_Float16)b;
  return __builtin_bit_cast(uint, h);
}
__device__ __forceinline__ float2 up2(uint u) {
  half2v h = __builtin_bit_cast(half2v, u);
  return make_float2((float)h.x, (float)h.y);
}

// 8-batch x 1-kpair dot: acc[c] += act_pair(c) . w_pair
__device__ __forceinline__ void dot8(uint4 aA, uint4 aB, uint wp, float* acc) {
#if __has_builtin(__builtin_amdgcn_fdot2)
  half2v w = __builtin_bit_cast(half2v, wp);
  acc[0] = __builtin_amdgcn_fdot2(__builtin_bit_cast(half2v, aA.x), w, acc[0], false);
  acc[1] = __builtin_amdgcn_fdot2(__builtin_bit_cast(half2v, aA.y), w, acc[1], false);
  acc[2] = __builtin_amdgcn_fdot2(__builtin_bit_cast(half2v, aA.z), w, acc[2], false);
  acc[3] = __builtin_amdgcn_fdot2(__builtin_bit_cast(half2v, aA.w), w, acc[3], false);
  acc[4] = __builtin_amdgcn_fdot2(__builtin_bit_cast(half2v, aB.x), w, acc[4], false);
  acc[5] = __builtin_amdgcn_fdot2(__builtin_bit_cast(half2v, aB.y), w, acc[5], false);
  acc[6] = __builtin_amdgcn_fdot2(__builtin_bit_cast(half2v, aB.z), w, acc[6], false);
  acc[7] = __builtin_amdgcn_fdot2(__builtin_bit_cast(half2v, aB.w), w, acc[7], false);
#else
  float2 w = up2(wp); float2 v;
  v = up2(aA.x); acc[0] = fmaf(v.x, w.x, fmaf(v.y, w.y, acc[0]));
  v = up2(aA.y); acc[1] = fmaf(v.x, w.x, fmaf(v.y, w.y, acc[1]));
  v = up2(aA.z); acc[2] = fmaf(v.x, w.x, fmaf(v.y, w.y, acc[2]));
  v = up2(aA.w); acc[3] = fmaf(v.x, w.x, fmaf(v.y, w.y, acc[3]));
  v = up2(aB.x); acc[4] = fmaf(v.x, w.x, fmaf(v.y, w.y, acc[4]));
  v = up2(aB.y); acc[5] = fmaf(v.x, w.x, fmaf(v.y, w.y, acc[5]));
  v = up2(aB.z); acc[6] = fmaf(v.x, w.x, fmaf(v.y, w.y, acc[6]));
  v = up2(aB.w); acc[7] = fmaf(v.x, w.x, fmaf(v.y, w.y, acc[7]));
#endif
}

// decentralized barrier: every wave polls all 256 padded flags (4 per lane)
__device__ __forceinline__ void wait_all(int pid) {
  const int l = threadIdx.x & 63;
  const int* f = &g_flags[l * PAD];
  int guard = 0;
  for (;;) {
    int m0 = __hip_atomic_load(f,             __ATOMIC_RELAXED, __HIP_MEMORY_SCOPE_AGENT);
    int m1 = __hip_atomic_load(f +  64 * PAD, __ATOMIC_RELAXED, __HIP_MEMORY_SCOPE_AGENT);
    int m2 = __hip_atomic_load(f + 128 * PAD, __ATOMIC_RELAXED, __HIP_MEMORY_SCOPE_AGENT);
    int m3 = __hip_atomic_load(f + 192 * PAD, __ATOMIC_RELAXED, __HIP_MEMORY_SCOPE_AGENT);
    int mn = m0 < m1 ? m0 : m1; int mn2 = m2 < m3 ? m2 : m3;
    mn = mn < mn2 ? mn : mn2;
    if (__all(mn >= pid)) break;
    __builtin_amdgcn_s_sleep(2);
    if (++guard > SPIN_MAX) break;
  }
  __threadfence();   // acquire
}

// ---------------- setup ----------------
__global__ void setup_kernel(float* __restrict__ out, int T) {
  int idx = blockIdx.x * blockDim.x + threadIdx.x;
  int n   = gridDim.x * blockDim.x;
  for (int i = idx; i < 256 * 128; i += n) {
    g_h0P[0][i] = 0u; g_h0P[1][i] = 0u;
    g_h1P[0][i] = 0u; g_h1P[1][i] = 0u;
  }
  for (int t = idx; t < T; t += n) out[BATCH * T * SSZ + t] = (float)t * 0.1f;
  for (int i = idx; i < NB * PAD; i += n) g_flags[i] = 0;
}

// ---------------- Wcomb = 0.1 * W0s @ Wfc ----------------
__global__ void wcomb_kernel(const float* __restrict__ Wih0, const float* __restrict__ Wfc) {
  int idx = blockIdx.x * blockDim.x + threadIdx.x;
  int row = idx >> 9, k = idx & (HID - 1);
  float a = 0.f;
#pragma unroll
  for (int m = 0; m < SSZ; m++) a += Wih0[row * (XSZ + SSZ) + XSZ + m] * Wfc[m * HID + k];
  g_Wcomb[idx] = 0.1f * a;
}

// ---------------- persistent RNN kernel ----------------
__global__ __launch_bounds__(BT, 4) void persist_kernel(
    const float* __restrict__ x,    const float* __restrict__ s0,
    const float* __restrict__ Wih0, const float* __restrict__ Whh0,
    const float* __restrict__ bih0, const float* __restrict__ bhh0,
    const float* __restrict__ Wih1, const float* __restrict__ Whh1,
    const float* __restrict__ bih1, const float* __restrict__ bhh1,
    const float* __restrict__ Wfc,  const float* __restrict__ bfc,
    float* __restrict__ out, int T)
{
  __shared__ uint  lw[4][8][256];     // f16 weight pairs: 0:w0h 1:wcomb 2:w1a 3:w1b
  __shared__ float gbuf[8][8][128];   // [ks][rid][batch] partials
  __shared__ float sbase[8][128];     // x.W + biases (layer0)
  __shared__ float c0s[2][128], c1s[2][128];
  __shared__ float b1s[8], ucs[8];

  const int bk  = blockIdx.x;
  const int tid = threadIdx.x;
  const int ks  = tid >> 7;          // 0..7 K-slice (0-3: mat A, 4-7: mat B)
  const int rid = (tid >> 4) & 7;    // gate-row within block
  const int bo  = tid & 15;          // batch oct (8 batch)
  const int mb  = (ks & 3) * 64;     // k-pair base within matrix

  // ---- stage weights to LDS as f16 pairs ----
  for (int e = tid; e < 4 * 8 * 256; e += BT) {
    int mat = e >> 11, r = (e >> 8) & 7, m = e & 255;
    int row = (r >> 1) * HID + 2 * bk + (r & 1);
    const float* src = (mat == 0) ? &Whh0[row * HID]
                     : (mat == 1) ? &g_Wcomb[row * HID]
                     : (mat == 2) ? &Wih1[row * HID] : &Whh1[row * HID];
    lw[mat][r][m] = pack_f16(src[2 * m], src[2 * m + 1]);
  }
  // ---- base = x.W0x + biases, per (rid, b) ----
  {
    int r = tid >> 7, b = tid & 127;
    int row = (r >> 1) * HID + 2 * bk + (r & 1);
    float a = bih0[row] + bhh0[row];
    const float* wr = Wih0 + row * (XSZ + SSZ);
#pragma unroll 4
    for (int k = 0; k < XSZ; k++) a = fmaf(wr[k], x[b * XSZ + k], a);
    sbase[r][b] = a;
  }
  if (tid < 8) {
    int row = (tid >> 1) * HID + 2 * bk + (tid & 1);
    b1s[tid] = bih1[row] + bhh1[row];
    float uc = 0.f;
    const float* ws = Wih0 + row * (XSZ + SSZ) + XSZ;
#pragma unroll
    for (int m = 0; m < SSZ; m++) uc = fmaf(ws[m], bfc[m], uc);
    ucs[tid] = 0.1f * uc;
  }
  __syncthreads();

  // ---- per-batch state (tid<128): u = W0s.s0 - uconst ; c = 0 ----
  float u[8];
  if (tid < 128) {
    int b = tid;
#pragma unroll
    for (int r = 0; r < 8; r++) {
      int row = (r >> 1) * HID + 2 * bk + (r & 1);
      const float* ws = Wih0 + row * (XSZ + SSZ) + XSZ;
      float a = 0.f;
#pragma unroll
      for (int m = 0; m < SSZ; m++) a = fmaf(ws[m], s0[b * SSZ + m], a);
      u[r] = a - ucs[r];
    }
    c0s[0][b] = 0.f; c0s[1][b] = 0.f;
    c1s[0][b] = 0.f; c1s[1][b] = 0.f;
  }

  // ---- fc lane state (wave 15 of blocks 128..255) ----
  const bool fcw = (bk >= 128) && (tid >= 960);
  const int  fb = bk - 128, lane = tid & 63, fs = lane & 15, fq = lane >> 4;
  float s_reg = 0.f;
  if (fcw && lane < SSZ) s_reg = s0[fb * SSZ + lane];

  const int matA = (ks < 4) ? 0 : 1;
  const int matB = (ks < 4) ? 2 : 3;

  int p = 0;
  for (int t = 0; t < T; ++t) {
    // ================= phase A =================
    if (ks < 4) wait_all(2 * t - 1);      // h0_{t-1} ready
    else {
      wait_all(2 * t);                    // h1_{t-1}, h1Nh ready
      if (fcw && t > 0) {                 // fc for step t-1
        const uint*  hp = g_h1Nh + fb * 256 + fq * 64;
        const float* wf = Wfc + fs * HID + fq * 128;
        float acc = 0.f;
#pragma unroll
        for (int i = 0; i < 64; i += 4) {
          uint4 a = *(const uint4*)(hp + i);
          float4 w0 = *(const float4*)(wf + 2 * i);
          float4 w1 = *(const float4*)(wf + 2 * i + 4);
          float2 v;
          v = up2(a.x); acc = fmaf(v.x, w0.x, fmaf(v.y, w0.y, acc));
          v = up2(a.y); acc = fmaf(v.x, w0.z, fmaf(v.y, w0.w, acc));
          v = up2(a.z); acc = fmaf(v.x, w1.x, fmaf(v.y, w1.y, acc));
          v = up2(a.w); acc = fmaf(v.x, w1.z, fmaf(v.y, w1.w, acc));
        }
        acc += __shfl_xor(acc, 16);
        acc += __shfl_xor(acc, 32);
        if (lane < SSZ) {
          float so = acc + bfc[fs];
          s_reg += 0.1f * so;
          out[fb * (T * SSZ) + (t - 1) * SSZ + fs] = s_reg;
          out[BATCH * T * SSZ + T + fb * (T * SSZ) + (t - 1) * SSZ + fs] = so;
        }
      }
    }
    {
      const uint* act = (ks < 4) ? g_h0P[p] : g_h1P[p];
      const uint* ap  = act + mb * 128 + bo * 8;
      const uint* wr  = &lw[matA][rid][mb];
      float acc[8] = {0,0,0,0,0,0,0,0};
#pragma unroll 4
      for (int i = 0; i < 64; i++) {
        uint4 aA = *(const uint4*)(ap);
        uint4 aB = *(const uint4*)(ap + 4);
        dot8(aA, aB, wr[i], acc);
        ap += 128;
      }
      *(float4*)&gbuf[ks][rid][bo * 8]     = make_float4(acc[0], acc[1], acc[2], acc[3]);
      *(float4*)&gbuf[ks][rid][bo * 8 + 4] = make_float4(acc[4], acc[5], acc[6], acc[7]);
    }
    __syncthreads();
    if (tid < 128) {
      int b = tid;
      float pre[8];
#pragma unroll
      for (int r = 0; r < 8; r++) {
        float s1 = gbuf[0][r][b] + gbuf[1][r][b] + gbuf[2][r][b] + gbuf[3][r][b];
        float s2 = gbuf[4][r][b] + gbuf[5][r][b] + gbuf[6][r][b] + gbuf[7][r][b];
        u[r] += s2 + ucs[r];
        pre[r] = sbase[r][b] + s1 + u[r];
      }
      float h[2];
#pragma unroll
      for (int jj = 0; jj < 2; jj++) {
        float c = c0s[jj][b];
        c = sigf(pre[2 + jj]) * c + sigf(pre[0 + jj]) * tanh_fast(pre[4 + jj]);
        c0s[jj][b] = c;
        h[jj] = sigf(pre[6 + jj]) * tanh_fast(c);
      }
      g_h0P[p ^ 1][bk * 128 + b] = pack_f16(h[0], h[1]);
    }
    __syncthreads();
    if (tid == 0) {
      __threadfence();
      __hip_atomic_store(&g_flags[bk * PAD], 2 * t + 1, __ATOMIC_RELAXED, __HIP_MEMORY_SCOPE_AGENT);
    }

    // ================= phase B =================
    if (ks < 4) wait_all(2 * t + 1);      // h0_t ready (ks>=4 reads old h1: no wait)
    {
      const uint* act = (ks < 4) ? g_h0P[p ^ 1] : g_h1P[p];
      const uint* ap  = act + mb * 128 + bo * 8;
      const uint* wr  = &lw[matB][rid][mb];
      float acc[8] = {0,0,0,0,0,0,0,0};
#pragma unroll 4
      for (int i = 0; i < 64; i++) {
        uint4 aA = *(const uint4*)(ap);
        uint4 aB = *(const uint4*)(ap + 4);
        dot8(aA, aB, wr[i], acc);
        ap += 128;
      }
      *(float4*)&gbuf[ks][rid][bo * 8]     = make_float4(acc[0], acc[1], acc[2], acc[3]);
      *(float4*)&gbuf[ks][rid][bo * 8 + 4] = make_float4(acc[4], acc[5], acc[6], acc[7]);
    }
    __syncthreads();
    if (tid < 128) {
      int b = tid;
      float pre[8];
#pragma unroll
      for (int r = 0; r < 8; r++) {
        float s1 = gbuf[0][r][b] + gbuf[1][r][b] + gbuf[2][r][b] + gbuf[3][r][b];
        float s2 = gbuf[4][r][b] + gbuf[5][r][b] + gbuf[6][r][b] + gbuf[7][r][b];
        pre[r] = b1s[r] + s1 + s2;
      }
      float h[2];
#pragma unroll
      for (int jj = 0; jj < 2; jj++) {
        float c = c1s[jj][b];
        c = sigf(pre[2 + jj]) * c + sigf(pre[0 + jj]) * tanh_fast(pre[4 + jj]);
        c1s[jj][b] = c;
        h[jj] = sigf(pre[6 + jj]) * tanh_fast(c);
      }
      uint pk = pack_f16(h[0], h[1]);
      g_h1P[p ^ 1][bk * 128 + b] = pk;
      g_h1Nh[b * 256 + bk] = pk;
    }
    __syncthreads();
    if (tid == 0) {
      __threadfence();
      __hip_atomic_store(&g_flags[bk * PAD], 2 * t + 2, __ATOMIC_RELAXED, __HIP_MEMORY_SCOPE_AGENT);
    }
    p ^= 1;
  }

  // ---- final fc for step T-1 ----
  if (fcw) {
    wait_all(2 * T);
    const uint*  hp = g_h1Nh + fb * 256 + fq * 64;
    const float* wf = Wfc + fs * HID + fq * 128;
    float acc = 0.f;
#pragma unroll
    for (int i = 0; i < 64; i += 4) {
      uint4 a = *(const uint4*)(hp + i);
      float4 w0 = *(const float4*)(wf + 2 * i);
      float4 w1 = *(const float4*)(wf + 2 * i + 4);
      float2 v;
      v = up2(a.x); acc = fmaf(v.x, w0.x, fmaf(v.y, w0.y, acc));
      v = up2(a.y); acc = fmaf(v.x, w0.z, fmaf(v.y, w0.w, acc));
      v = up2(a.z); acc = fmaf(v.x, w1.x, fmaf(v.y, w1.y, acc));
      v = up2(a.w); acc = fmaf(v.x, w1.z, fmaf(v.y, w1.w, acc));
    }
    acc += __shfl_xor(acc, 16);
    acc += __shfl_xor(acc, 32);
    if (lane < SSZ) {
      float so = acc + bfc[fs];
      s_reg += 0.1f * so;
      out[fb * (T * SSZ) + (T - 1) * SSZ + fs] = s_reg;
      out[BATCH * T * SSZ + T + fb * (T * SSZ) + (T - 1) * SSZ + fs] = so;
    }
  }
}

extern "C" void kernel_launch(void* const* d_in, const int* in_sizes, int n_in,
                              void* d_out, int out_size, void* d_ws, size_t ws_size,
                              hipStream_t stream) {
  const float* x    = (const float*)d_in[0];
  const float* s0   = (const float*)d_in[1];
  const float* Wih0 = (const float*)d_in[2];
  const float* Whh0 = (const float*)d_in[3];
  const float* bih0 = (const float*)d_in[4];
  const float* bhh0 = (const float*)d_in[5];
  const float* Wih1 = (const float*)d_in[6];
  const float* Whh1 = (const float*)d_in[7];
  const float* bih1 = (const float*)d_in[8];
  const float* bhh1 = (const float*)d_in[9];
  const float* Wfc  = (const float*)d_in[10];
  const float* bfc  = (const float*)d_in[11];
  float* out = (float*)d_out;

  const int T = out_size / (2 * BATCH * SSZ + 1);

  setup_kernel<<<64, 256, 0, stream>>>(out, T);
  wcomb_kernel<<<(4 * HID * HID) / 256, 256, 0, stream>>>(Wih0, Wfc);
  persist_kernel<<<NB, BT, 0, stream>>>(x, s0, Wih0, Whh0, bih0, bhh0,
                                        Wih1, Whh1, bih1, bhh1, Wfc, bfc, out, T);
}

// Round 5
// 20615.948 us; speedup vs baseline: 1.4397x; 1.4397x over previous
//
#include <hip/hip_runtime.h>

#define NB    256
#define BT    1024
#define BATCH 128
#define HID   512
#define XSZ   64
#define SSZ   16
#define PAD   32
#define SPIN_MAX (1 << 18)

typedef unsigned int uint;
typedef _Float16 half2v __attribute__((ext_vector_type(2)));

// ---------------- persistent device state ----------------
// act layout: [q][b] uint4, q = kpair/4 (64), b = batch (128); uint = f16 pair (cols 2m,2m+1)
__device__ __align__(16) uint4 g_h0Q[2][64 * 128];
__device__ __align__(16) uint4 g_h1Q[2][64 * 128];
__device__ __align__(16) float g_Wcomb[4 * HID * HID];   // 0.1 * W0s @ Wfc [2048][512]
__device__ int g_flags[NB * PAD];

// ---------------- helpers ----------------
__device__ __forceinline__ float sigf(float x) { return 1.f / (1.f + __expf(-x)); }
__device__ __forceinline__ float tanh_fast(float x) {
  float ax = fabsf(x); float e = __expf(-2.f * ax);
  return copysignf((1.f - e) / (1.f + e), x);
}
__device__ __forceinline__ uint pack_f16(float a, float b) {
  half2v h; h.x = (_Float16)a; h.y = (_Float16)b;
  return __builtin_bit_cast(uint, h);
}
__device__ __forceinline__ float2 up2(uint u) {
  half2v h = __builtin_bit_cast(half2v, u);
  return make_float2((float)h.x, (float)h.y);
}
__device__ __forceinline__ float fdot2(uint a, uint w, float c) {
#if __has_builtin(__builtin_amdgcn_fdot2)
  return __builtin_amdgcn_fdot2(__builtin_bit_cast(half2v, a),
                                __builtin_bit_cast(half2v, w), c, false);
#else
  float2 av = up2(a), wv = up2(w);
  return fmaf(av.x, wv.x, fmaf(av.y, wv.y, c));
#endif
}
// one act f16-pair against 8 rows of weights
__device__ __forceinline__ void dot8(uint a, uint4 w0, uint4 w1, float* acc) {
  acc[0] = fdot2(a, w0.x, acc[0]); acc[1] = fdot2(a, w0.y, acc[1]);
  acc[2] = fdot2(a, w0.z, acc[2]); acc[3] = fdot2(a, w0.w, acc[3]);
  acc[4] = fdot2(a, w1.x, acc[4]); acc[5] = fdot2(a, w1.y, acc[5]);
  acc[6] = fdot2(a, w1.z, acc[6]); acc[7] = fdot2(a, w1.w, acc[7]);
}
// 16 uint4 act elements (64 kpairs) x 8 rows
__device__ __forceinline__ void dots16(const uint4* __restrict__ ap,   // + q0*128 + b
                                       const uint*  __restrict__ wb,   // &lwT[mat][kp0][0]
                                       float* __restrict__ acc) {
#pragma unroll 4
  for (int i = 0; i < 16; ++i) {
    uint4 A = ap[i * 128];
    const uint4* w4 = (const uint4*)(wb + 32 * i);
    dot8(A.x, w4[0], w4[1], acc);
    dot8(A.y, w4[2], w4[3], acc);
    dot8(A.z, w4[4], w4[5], acc);
    dot8(A.w, w4[6], w4[7], acc);
  }
}

// decentralized barrier: every wave polls all 256 padded flags (4 per lane)
__device__ __forceinline__ void wait_all(int pid) {
  const int l = threadIdx.x & 63;
  const int* f = &g_flags[l * PAD];
  int guard = 0;
  for (;;) {
    int m0 = __hip_atomic_load(f,             __ATOMIC_RELAXED, __HIP_MEMORY_SCOPE_AGENT);
    int m1 = __hip_atomic_load(f +  64 * PAD, __ATOMIC_RELAXED, __HIP_MEMORY_SCOPE_AGENT);
    int m2 = __hip_atomic_load(f + 128 * PAD, __ATOMIC_RELAXED, __HIP_MEMORY_SCOPE_AGENT);
    int m3 = __hip_atomic_load(f + 192 * PAD, __ATOMIC_RELAXED, __HIP_MEMORY_SCOPE_AGENT);
    int mn = m0 < m1 ? m0 : m1; int mn2 = m2 < m3 ? m2 : m3;
    mn = mn < mn2 ? mn : mn2;
    if (__all(mn >= pid)) break;
    __builtin_amdgcn_s_sleep(1);
    if (++guard > SPIN_MAX) break;
  }
  __threadfence();   // acquire
}

// ---------------- setup ----------------
__global__ void setup_kernel(float* __restrict__ out, int T) {
  int idx = blockIdx.x * blockDim.x + threadIdx.x;
  int n   = gridDim.x * blockDim.x;
  uint* z0 = (uint*)g_h0Q;
  uint* z1 = (uint*)g_h1Q;
  for (int i = idx; i < 2 * 64 * 128 * 4; i += n) { z0[i] = 0u; z1[i] = 0u; }
  for (int t = idx; t < T; t += n) out[BATCH * T * SSZ + t] = (float)t * 0.1f;
  for (int i = idx; i < NB * PAD; i += n) g_flags[i] = 0;
}

// ---------------- Wcomb = 0.1 * W0s @ Wfc ----------------
__global__ void wcomb_kernel(const float* __restrict__ Wih0, const float* __restrict__ Wfc) {
  int idx = blockIdx.x * blockDim.x + threadIdx.x;
  int row = idx >> 9, k = idx & (HID - 1);
  float a = 0.f;
#pragma unroll
  for (int m = 0; m < SSZ; m++) a += Wih0[row * (XSZ + SSZ) + XSZ + m] * Wfc[m * HID + k];
  g_Wcomb[idx] = 0.1f * a;
}

// ---------------- persistent RNN kernel ----------------
__global__ __launch_bounds__(BT, 4) void persist_kernel(
    const float* __restrict__ x,    const float* __restrict__ s0,
    const float* __restrict__ Wih0, const float* __restrict__ Whh0,
    const float* __restrict__ bih0, const float* __restrict__ bhh0,
    const float* __restrict__ Wih1, const float* __restrict__ Whh1,
    const float* __restrict__ bih1, const float* __restrict__ bhh1,
    const float* __restrict__ Wfc,  const float* __restrict__ bfc,
    float* __restrict__ out, int T)
{
  __shared__ uint  lwT[4][256][8];    // [mat][kpair][row] f16 pairs: 0:W0h 1:Wcomb 2:W1a 3:W1b
  __shared__ float gbuf[8][8][128];   // [ks][row][b] partials
  __shared__ float sbase[8][128];     // x.W0x + biases
  __shared__ float c0s[2][128], c1s[2][128];
  __shared__ uint  wfcP[16][268];     // Wfc f16 pairs, padded rows (bank spread)
  __shared__ float b1s[8], ucs[8];

  const int bk  = blockIdx.x;
  const int tid = threadIdx.x;
  const int ks  = tid >> 7;        // K-slice 0..7 (0-3: mat A of phase, 4-7: mat B)
  const int b   = tid & 127;       // batch column
  const int q0  = (ks & 3) * 16;   // uint4-row base of this K-slice
  const int kp0 = (ks & 3) * 64;   // kpair base

  // ---- stage weights to LDS as f16 pairs (transposed: [kpair][row]) ----
  for (int e = tid; e < 4 * 256 * 8; e += BT) {
    int mat = e >> 11, kp = (e >> 3) & 255, r = e & 7;
    int row = (r >> 1) * HID + 2 * bk + (r & 1);
    const float* src = (mat == 0) ? &Whh0[row * HID]
                     : (mat == 1) ? &g_Wcomb[row * HID]
                     : (mat == 2) ? &Wih1[row * HID] : &Whh1[row * HID];
    lwT[mat][kp][r] = pack_f16(src[2 * kp], src[2 * kp + 1]);
  }
  for (int e = tid; e < 16 * 256; e += BT) {
    int fs_ = e >> 8, kp = e & 255;
    wfcP[fs_][kp] = pack_f16(Wfc[fs_ * HID + 2 * kp], Wfc[fs_ * HID + 2 * kp + 1]);
  }
  // ---- sbase = x.W0x + biases ----
  {
    int r = tid >> 7, bb = tid & 127;
    int row = (r >> 1) * HID + 2 * bk + (r & 1);
    float a = bih0[row] + bhh0[row];
    const float* wr = Wih0 + row * (XSZ + SSZ);
#pragma unroll 4
    for (int k = 0; k < XSZ; k++) a = fmaf(wr[k], x[bb * XSZ + k], a);
    sbase[r][bb] = a;
  }
  if (tid < 8) {
    int row = (tid >> 1) * HID + 2 * bk + (tid & 1);
    b1s[tid] = bih1[row] + bhh1[row];
    float uc = 0.f;
    const float* ws = Wih0 + row * (XSZ + SSZ) + XSZ;
#pragma unroll
    for (int m = 0; m < SSZ; m++) uc = fmaf(ws[m], bfc[m], uc);
    ucs[tid] = 0.1f * uc;
  }
  __syncthreads();

  // ---- per-batch carried state (tid<128): u = W0s.s0 - uconst ; c = 0 ----
  float u[8];
  if (tid < 128) {
#pragma unroll
    for (int r = 0; r < 8; r++) {
      int row = (r >> 1) * HID + 2 * bk + (r & 1);
      const float* ws = Wih0 + row * (XSZ + SSZ) + XSZ;
      float a = 0.f;
#pragma unroll
      for (int m = 0; m < SSZ; m++) a = fmaf(ws[m], s0[b * SSZ + m], a);
      u[r] = a - ucs[r];
    }
    c0s[0][b] = 0.f; c0s[1][b] = 0.f;
    c1s[0][b] = 0.f; c1s[1][b] = 0.f;
  }

  // ---- fc lane state (wave 15 of blocks 128..255; one batch row each) ----
  const bool fcw = (bk >= 128) && ((tid >> 6) == 15);
  const int  fb = bk - 128, lane = tid & 63, fs = lane & 15, fq = lane >> 4;
  float s_reg = 0.f, bfcj = 0.f;
  if (fcw && lane < SSZ) { s_reg = s0[fb * SSZ + lane]; bfcj = bfc[lane]; }

  // fc: so = Wfc.h1 + bfc ; s += 0.1*so ; write outputs for step tt
  auto fc_step = [&](int tt, const uint4* h1base) {
    const uint4* hp = h1base + fq * 16 * 128 + fb;
    const uint4* wp = (const uint4*)&wfcP[fs][fq * 64];
    float acc = 0.f;
#pragma unroll 4
    for (int i = 0; i < 16; ++i) {
      uint4 a = hp[i * 128];
      uint4 w = wp[i];
      acc = fdot2(a.x, w.x, acc); acc = fdot2(a.y, w.y, acc);
      acc = fdot2(a.z, w.z, acc); acc = fdot2(a.w, w.w, acc);
    }
    acc += __shfl_xor(acc, 16);
    acc += __shfl_xor(acc, 32);
    if (lane < SSZ) {
      float so = acc + bfcj;
      s_reg += 0.1f * so;
      out[fb * (T * SSZ) + tt * SSZ + fs] = s_reg;
      out[BATCH * T * SSZ + T + fb * (T * SSZ) + tt * SSZ + fs] = so;
    }
  };

  int p = 0;
  for (int t = 0; t < T; ++t) {
    // ================= phase A : gates0 =================
    if (ks >= 4) {
      wait_all(2 * t);                         // h1_{t-1} ready (only wait for ks>=4)
      if (fcw && t > 0) fc_step(t - 1, g_h1Q[p]);
    }
    {
      float acc[8] = {0, 0, 0, 0, 0, 0, 0, 0};
      const uint4* actQ = (ks < 4) ? g_h0Q[p] : g_h1Q[p];
      const uint*  wb   = &lwT[(ks < 4) ? 0 : 1][kp0][0];
      dots16(actQ + q0 * 128 + b, wb, acc);
#pragma unroll
      for (int r = 0; r < 8; r++) gbuf[ks][r][b] = acc[r];
    }
    __syncthreads();
    if (tid < 128) {
      float pre[8];
#pragma unroll
      for (int r = 0; r < 8; r++) {
        float s1 = gbuf[0][r][b] + gbuf[1][r][b] + gbuf[2][r][b] + gbuf[3][r][b];
        float s2 = gbuf[4][r][b] + gbuf[5][r][b] + gbuf[6][r][b] + gbuf[7][r][b];
        u[r] += s2 + ucs[r];
        pre[r] = sbase[r][b] + s1 + u[r];
      }
      float h[2];
#pragma unroll
      for (int jj = 0; jj < 2; jj++) {
        float c = c0s[jj][b];
        c = sigf(pre[2 + jj]) * c + sigf(pre[0 + jj]) * tanh_fast(pre[4 + jj]);
        c0s[jj][b] = c;
        h[jj] = sigf(pre[6 + jj]) * tanh_fast(c);
      }
      ((uint*)&g_h0Q[p ^ 1][(bk >> 2) * 128 + b])[bk & 3] = pack_f16(h[0], h[1]);
    }
    __syncthreads();
    if (tid == 0) {
      __threadfence();
      __hip_atomic_store(&g_flags[bk * PAD], 2 * t + 1, __ATOMIC_RELAXED, __HIP_MEMORY_SCOPE_AGENT);
    }

    // ================= phase B : gates1 =================
    if (ks < 4) wait_all(2 * t + 1);           // h0_t ready (ks>=4 reads old h1: no wait)
    {
      float acc[8] = {0, 0, 0, 0, 0, 0, 0, 0};
      const uint4* actQ = (ks < 4) ? g_h0Q[p ^ 1] : g_h1Q[p];
      const uint*  wb   = &lwT[(ks < 4) ? 2 : 3][kp0][0];
      dots16(actQ + q0 * 128 + b, wb, acc);
#pragma unroll
      for (int r = 0; r < 8; r++) gbuf[ks][r][b] = acc[r];
    }
    __syncthreads();
    if (tid < 128) {
      float pre[8];
#pragma unroll
      for (int r = 0; r < 8; r++) {
        float s1 = gbuf[0][r][b] + gbuf[1][r][b] + gbuf[2][r][b] + gbuf[3][r][b];
        float s2 = gbuf[4][r][b] + gbuf[5][r][b] + gbuf[6][r][b] + gbuf[7][r][b];
        pre[r] = b1s[r] + s1 + s2;
      }
      float h[2];
#pragma unroll
      for (int jj = 0; jj < 2; jj++) {
        float c = c1s[jj][b];
        c = sigf(pre[2 + jj]) * c + sigf(pre[0 + jj]) * tanh_fast(pre[4 + jj]);
        c1s[jj][b] = c;
        h[jj] = sigf(pre[6 + jj]) * tanh_fast(c);
      }
      ((uint*)&g_h1Q[p ^ 1][(bk >> 2) * 128 + b])[bk & 3] = pack_f16(h[0], h[1]);
    }
    __syncthreads();
    if (tid == 0) {
      __threadfence();
      __hip_atomic_store(&g_flags[bk * PAD], 2 * t + 2, __ATOMIC_RELAXED, __HIP_MEMORY_SCOPE_AGENT);
    }
    p ^= 1;
  }

  // ---- final fc for step T-1 (h1_{T-1} lives in g_h1Q[p] after the last flip) ----
  if (fcw) {
    wait_all(2 * T);
    fc_step(T - 1, g_h1Q[p]);
  }
}

extern "C" void kernel_launch(void* const* d_in, const int* in_sizes, int n_in,
                              void* d_out, int out_size, void* d_ws, size_t ws_size,
                              hipStream_t stream) {
  const float* x    = (const float*)d_in[0];
  const float* s0   = (const float*)d_in[1];
  const float* Wih0 = (const float*)d_in[2];
  const float* Whh0 = (const float*)d_in[3];
  const float* bih0 = (const float*)d_in[4];
  const float* bhh0 = (const float*)d_in[5];
  const float* Wih1 = (const float*)d_in[6];
  const float* Whh1 = (const float*)d_in[7];
  const float* bih1 = (const float*)d_in[8];
  const float* bhh1 = (const float*)d_in[9];
  const float* Wfc  = (const float*)d_in[10];
  const float* bfc  = (const float*)d_in[11];
  float* out = (float*)d_out;

  const int T = out_size / (2 * BATCH * SSZ + 1);

  setup_kernel<<<64, 256, 0, stream>>>(out, T);
  wcomb_kernel<<<(4 * HID * HID) / 256, 256, 0, stream>>>(Wih0, Wfc);
  persist_kernel<<<NB, BT, 0, stream>>>(x, s0, Wih0, Whh0, bih0, bhh0,
                                        Wih1, Whh1, bih1, bhh1, Wfc, bfc, out, T);
}

// Round 6
// 20405.205 us; speedup vs baseline: 1.4546x; 1.0103x over previous
//
#include <hip/hip_runtime.h>

#define NB    256
#define BT    1024
#define BATCH 128
#define HID   512
#define XSZ   64
#define SSZ   16
#define CPAD  32                 // ints per counter slot = 128B line
#define SPIN_MAX (1 << 17)

typedef unsigned int uint;
typedef _Float16 half2v __attribute__((ext_vector_type(2)));

// ---------------- persistent device state ----------------
// act layout: [q][b] uint4, q = kpair/4 (64), b = batch (128); uint = f16 pair (cols 2m,2m+1)
__device__ __align__(16) uint4 g_h0Q[2][64 * 128];
__device__ __align__(16) uint4 g_h1Q[2][64 * 128];
__device__ __align__(16) float g_Wcomb[4 * HID * HID];   // 0.1 * W0s @ Wfc [2048][512]
__device__ int g_cnt[512 * CPAD];                        // per-phase arrival counters

// ---------------- helpers ----------------
__device__ __forceinline__ float sigf(float x) { return 1.f / (1.f + __expf(-x)); }
__device__ __forceinline__ float tanh_fast(float x) {
  float ax = fabsf(x); float e = __expf(-2.f * ax);
  return copysignf((1.f - e) / (1.f + e), x);
}
__device__ __forceinline__ uint pack_f16(float a, float b) {
  half2v h; h.x = (_Float16)a; h.y = (_Float16)b;
  return __builtin_bit_cast(uint, h);
}
__device__ __forceinline__ float2 up2(uint u) {
  half2v h = __builtin_bit_cast(half2v, u);
  return make_float2((float)h.x, (float)h.y);
}
__device__ __forceinline__ float fdot2(uint a, uint w, float c) {
#if __has_builtin(__builtin_amdgcn_fdot2)
  return __builtin_amdgcn_fdot2(__builtin_bit_cast(half2v, a),
                                __builtin_bit_cast(half2v, w), c, false);
#else
  float2 av = up2(a), wv = up2(w);
  return fmaf(av.x, wv.x, fmaf(av.y, wv.y, c));
#endif
}
__device__ __forceinline__ void dot8(uint a, uint4 w0, uint4 w1, float* acc) {
  acc[0] = fdot2(a, w0.x, acc[0]); acc[1] = fdot2(a, w0.y, acc[1]);
  acc[2] = fdot2(a, w0.z, acc[2]); acc[3] = fdot2(a, w0.w, acc[3]);
  acc[4] = fdot2(a, w1.x, acc[4]); acc[5] = fdot2(a, w1.y, acc[5]);
  acc[6] = fdot2(a, w1.z, acc[6]); acc[7] = fdot2(a, w1.w, acc[7]);
}
__device__ __forceinline__ void dots16(const uint4* __restrict__ ap,
                                       const uint*  __restrict__ wb,
                                       float* __restrict__ acc) {
#pragma unroll 4
  for (int i = 0; i < 16; ++i) {
    uint4 A = ap[i * 128];
    const uint4* w4 = (const uint4*)(wb + 32 * i);
    dot8(A.x, w4[0], w4[1], acc);
    dot8(A.y, w4[2], w4[3], acc);
    dot8(A.z, w4[4], w4[5], acc);
    dot8(A.w, w4[6], w4[7], acc);
  }
}

// poll one counter line (all lanes same address -> 1 line request), then acquire
__device__ __forceinline__ void cnt_wait(int pid) {
  int guard = 0;
  while (__hip_atomic_load(&g_cnt[pid * CPAD], __ATOMIC_RELAXED, __HIP_MEMORY_SCOPE_AGENT) < NB) {
    __builtin_amdgcn_s_sleep(4);
    if (++guard > SPIN_MAX) break;
  }
  __threadfence();
}

// group wait: poller wave polls global counter, siblings spin on LDS release word
__device__ __forceinline__ void group_wait(int pid, int pw, int tid, int* rel) {
  if ((tid >> 6) == pw) {
    cnt_wait(pid);
    if ((tid & 63) == 0)
      __hip_atomic_store(&rel[pid & 1], pid, __ATOMIC_RELEASE, __HIP_MEMORY_SCOPE_WORKGROUP);
  } else {
    int guard = 0;
    while (__hip_atomic_load(&rel[pid & 1], __ATOMIC_ACQUIRE, __HIP_MEMORY_SCOPE_WORKGROUP) < pid) {
      __builtin_amdgcn_s_sleep(1);
      if (++guard > SPIN_MAX) break;
    }
    __threadfence();
  }
}

// ---------------- setup ----------------
__global__ void setup_kernel(float* __restrict__ out, int T) {
  int idx = blockIdx.x * blockDim.x + threadIdx.x;
  int n   = gridDim.x * blockDim.x;
  uint* z0 = (uint*)g_h0Q;
  uint* z1 = (uint*)g_h1Q;
  for (int i = idx; i < 2 * 64 * 128 * 4; i += n) { z0[i] = 0u; z1[i] = 0u; }
  for (int t = idx; t < T; t += n) out[BATCH * T * SSZ + t] = (float)t * 0.1f;
  for (int i = idx; i < 512 * CPAD; i += n) g_cnt[i] = 0;
}

// ---------------- Wcomb = 0.1 * W0s @ Wfc ----------------
__global__ void wcomb_kernel(const float* __restrict__ Wih0, const float* __restrict__ Wfc) {
  int idx = blockIdx.x * blockDim.x + threadIdx.x;
  int row = idx >> 9, k = idx & (HID - 1);
  float a = 0.f;
#pragma unroll
  for (int m = 0; m < SSZ; m++) a += Wih0[row * (XSZ + SSZ) + XSZ + m] * Wfc[m * HID + k];
  g_Wcomb[idx] = 0.1f * a;
}

// ---------------- persistent RNN kernel ----------------
__global__ __launch_bounds__(BT, 4) void persist_kernel(
    const float* __restrict__ x,    const float* __restrict__ s0,
    const float* __restrict__ Wih0, const float* __restrict__ Whh0,
    const float* __restrict__ bih0, const float* __restrict__ bhh0,
    const float* __restrict__ Wih1, const float* __restrict__ Whh1,
    const float* __restrict__ bih1, const float* __restrict__ bhh1,
    const float* __restrict__ Wfc,  const float* __restrict__ bfc,
    float* __restrict__ out, int T)
{
  __shared__ uint  lwT[4][256][8];    // [mat][kpair][row] f16 pairs: 0:W0h 1:Wcomb 2:W1a 3:W1b
  __shared__ float gbuf[8][8][128];   // [ks][row][b] partials
  __shared__ float sbase[8][128];     // x.W0x + biases
  __shared__ float c0s[2][128], c1s[2][128];
  __shared__ uint  wfcP[16][268];     // Wfc f16 pairs, padded rows
  __shared__ float b1s[8], ucs[8];
  __shared__ int   rel[2];            // LDS release words (even/odd pid)

  const int bk  = blockIdx.x;
  const int tid = threadIdx.x;
  const int ks  = tid >> 7;        // K-slice 0..7 (0-3: h0-K, 4-7: h1-K)
  const int b   = tid & 127;       // batch column
  const int q0  = (ks & 3) * 16;   // uint4-row base of this K-slice
  const int kp0 = (ks & 3) * 64;   // kpair base

  if (tid == 0) { rel[0] = -1; rel[1] = -1; }

  // ---- stage weights to LDS as f16 pairs (transposed: [kpair][row]) ----
  for (int e = tid; e < 4 * 256 * 8; e += BT) {
    int mat = e >> 11, kp = (e >> 3) & 255, r = e & 7;
    int row = (r >> 1) * HID + 2 * bk + (r & 1);
    const float* src = (mat == 0) ? &Whh0[row * HID]
                     : (mat == 1) ? &g_Wcomb[row * HID]
                     : (mat == 2) ? &Wih1[row * HID] : &Whh1[row * HID];
    lwT[mat][kp][r] = pack_f16(src[2 * kp], src[2 * kp + 1]);
  }
  for (int e = tid; e < 16 * 256; e += BT) {
    int fs_ = e >> 8, kp = e & 255;
    wfcP[fs_][kp] = pack_f16(Wfc[fs_ * HID + 2 * kp], Wfc[fs_ * HID + 2 * kp + 1]);
  }
  // ---- sbase = x.W0x + biases ----
  {
    int r = tid >> 7, bb = tid & 127;
    int row = (r >> 1) * HID + 2 * bk + (r & 1);
    float a = bih0[row] + bhh0[row];
    const float* wr = Wih0 + row * (XSZ + SSZ);
#pragma unroll 4
    for (int k = 0; k < XSZ; k++) a = fmaf(wr[k], x[bb * XSZ + k], a);
    sbase[r][bb] = a;
  }
  if (tid < 8) {
    int row = (tid >> 1) * HID + 2 * bk + (tid & 1);
    b1s[tid] = bih1[row] + bhh1[row];
    float uc = 0.f;
    const float* ws = Wih0 + row * (XSZ + SSZ) + XSZ;
#pragma unroll
    for (int m = 0; m < SSZ; m++) uc = fmaf(ws[m], bfc[m], uc);
    ucs[tid] = 0.1f * uc;
  }
  __syncthreads();

  // ---- per-batch carried state (tid<128): u = W0s.s0 - uconst ; c = 0 ----
  float u[8];
  if (tid < 128) {
#pragma unroll
    for (int r = 0; r < 8; r++) {
      int row = (r >> 1) * HID + 2 * bk + (r & 1);
      const float* ws = Wih0 + row * (XSZ + SSZ) + XSZ;
      float a = 0.f;
#pragma unroll
      for (int m = 0; m < SSZ; m++) a = fmaf(ws[m], s0[b * SSZ + m], a);
      u[r] = a - ucs[r];
    }
    c0s[0][b] = 0.f; c0s[1][b] = 0.f;
    c1s[0][b] = 0.f; c1s[1][b] = 0.f;
  }

  // ---- fc lane state (wave 15 of blocks 128..255; one batch row each) ----
  const bool fcw = (bk >= 128) && ((tid >> 6) == 15);
  const int  fb = bk - 128, lane = tid & 63, fs = lane & 15, fq = lane >> 4;
  float s_reg = 0.f, bfcj = 0.f;
  if (fcw && lane < SSZ) { s_reg = s0[fb * SSZ + lane]; bfcj = bfc[lane]; }

  auto fc_step = [&](int tt, const uint4* h1base) {
    const uint4* hp = h1base + fq * 16 * 128 + fb;
    const uint4* wp = (const uint4*)&wfcP[fs][fq * 64];
    float acc = 0.f;
#pragma unroll 4
    for (int i = 0; i < 16; ++i) {
      uint4 a = hp[i * 128];
      uint4 w = wp[i];
      acc = fdot2(a.x, w.x, acc); acc = fdot2(a.y, w.y, acc);
      acc = fdot2(a.z, w.z, acc); acc = fdot2(a.w, w.w, acc);
    }
    acc += __shfl_xor(acc, 16);
    acc += __shfl_xor(acc, 32);
    if (lane < SSZ) {
      float so = acc + bfcj;
      s_reg += 0.1f * so;
      out[fb * (T * SSZ) + tt * SSZ + fs] = s_reg;
      out[BATCH * T * SSZ + T + fb * (T * SSZ) + tt * SSZ + fs] = so;
    }
  };

  int p = 0;
  for (int t = 0; t < T; ++t) {
    // ================= phase A : gates0 =================
    if (ks >= 4 && t > 0) group_wait(2 * t, 8, tid, rel);   // h1_{t-1} ready
    {
      float acc[8] = {0, 0, 0, 0, 0, 0, 0, 0};
      const uint4* actQ = (ks < 4) ? g_h0Q[p] : g_h1Q[p];
      const uint*  wb   = &lwT[(ks < 4) ? 0 : 1][kp0][0];
      dots16(actQ + q0 * 128 + b, wb, acc);
#pragma unroll
      for (int r = 0; r < 8; r++) gbuf[ks][r][b] = acc[r];
    }
    __syncthreads();
    if (tid < 128) {
      float pre[8];
#pragma unroll
      for (int r = 0; r < 8; r++) {
        float s1 = gbuf[0][r][b] + gbuf[1][r][b] + gbuf[2][r][b] + gbuf[3][r][b];
        float s2 = gbuf[4][r][b] + gbuf[5][r][b] + gbuf[6][r][b] + gbuf[7][r][b];
        u[r] += s2 + ucs[r];
        pre[r] = sbase[r][b] + s1 + u[r];
      }
      float h[2];
#pragma unroll
      for (int jj = 0; jj < 2; jj++) {
        float c = c0s[jj][b];
        c = sigf(pre[2 + jj]) * c + sigf(pre[0 + jj]) * tanh_fast(pre[4 + jj]);
        c0s[jj][b] = c;
        h[jj] = sigf(pre[6 + jj]) * tanh_fast(c);
      }
      ((uint*)&g_h0Q[p ^ 1][(bk >> 2) * 128 + b])[bk & 3] = pack_f16(h[0], h[1]);
    }
    __syncthreads();
    if (tid == 0) {
      __threadfence();
      __hip_atomic_fetch_add(&g_cnt[(2 * t + 1) * CPAD], 1, __ATOMIC_RELAXED, __HIP_MEMORY_SCOPE_AGENT);
    }

    // ================= phase B : gates1 =================
    if (ks < 4) group_wait(2 * t + 1, 0, tid, rel);         // h0_t ready
    {
      float acc[8] = {0, 0, 0, 0, 0, 0, 0, 0};
      const uint4* actQ = (ks < 4) ? g_h0Q[p ^ 1] : g_h1Q[p];
      const uint*  wb   = &lwT[(ks < 4) ? 2 : 3][kp0][0];
      dots16(actQ + q0 * 128 + b, wb, acc);
#pragma unroll
      for (int r = 0; r < 8; r++) gbuf[ks][r][b] = acc[r];
    }
    if (fcw && t > 0) fc_step(t - 1, g_h1Q[p]);   // fc for step t-1, in phase-B slack
    __syncthreads();
    if (tid < 128) {
      float pre[8];
#pragma unroll
      for (int r = 0; r < 8; r++) {
        float s1 = gbuf[0][r][b] + gbuf[1][r][b] + gbuf[2][r][b] + gbuf[3][r][b];
        float s2 = gbuf[4][r][b] + gbuf[5][r][b] + gbuf[6][r][b] + gbuf[7][r][b];
        pre[r] = b1s[r] + s1 + s2;
      }
      float h[2];
#pragma unroll
      for (int jj = 0; jj < 2; jj++) {
        float c = c1s[jj][b];
        c = sigf(pre[2 + jj]) * c + sigf(pre[0 + jj]) * tanh_fast(pre[4 + jj]);
        c1s[jj][b] = c;
        h[jj] = sigf(pre[6 + jj]) * tanh_fast(c);
      }
      ((uint*)&g_h1Q[p ^ 1][(bk >> 2) * 128 + b])[bk & 3] = pack_f16(h[0], h[1]);
    }
    __syncthreads();
    if (tid == 0) {
      __threadfence();
      __hip_atomic_fetch_add(&g_cnt[(2 * t + 2) * CPAD], 1, __ATOMIC_RELAXED, __HIP_MEMORY_SCOPE_AGENT);
    }
    p ^= 1;
  }

  // ---- final fc for step T-1 ----
  if (fcw) {
    cnt_wait(2 * T);
    fc_step(T - 1, g_h1Q[p]);
  }
}

extern "C" void kernel_launch(void* const* d_in, const int* in_sizes, int n_in,
                              void* d_out, int out_size, void* d_ws, size_t ws_size,
                              hipStream_t stream) {
  const float* x    = (const float*)d_in[0];
  const float* s0   = (const float*)d_in[1];
  const float* Wih0 = (const float*)d_in[2];
  const float* Whh0 = (const float*)d_in[3];
  const float* bih0 = (const float*)d_in[4];
  const float* bhh0 = (const float*)d_in[5];
  const float* Wih1 = (const float*)d_in[6];
  const float* Whh1 = (const float*)d_in[7];
  const float* bih1 = (const float*)d_in[8];
  const float* bhh1 = (const float*)d_in[9];
  const float* Wfc  = (const float*)d_in[10];
  const float* bfc  = (const float*)d_in[11];
  float* out = (float*)d_out;

  const int T = out_size / (2 * BATCH * SSZ + 1);

  setup_kernel<<<64, 256, 0, stream>>>(out, T);
  wcomb_kernel<<<(4 * HID * HID) / 256, 256, 0, stream>>>(Wih0, Wfc);
  persist_kernel<<<NB, BT, 0, stream>>>(x, s0, Wih0, Whh0, bih0, bhh0,
                                        Wih1, Whh1, bih1, bhh1, Wfc, bfc, out, T);
}

// Round 7
// 5469.784 us; speedup vs baseline: 5.4264x; 3.7305x over previous
//
#include <hip/hip_runtime.h>

#define NB    256
#define BT    1024
#define BATCH 128
#define HID   512
#define XSZ   64
#define SSZ   16
#define CPAD  32                 // ints per counter slot = 128B line
#define SPIN_MAX (1 << 17)

typedef unsigned int uint;
typedef unsigned long long ulong64;
typedef _Float16 half2v __attribute__((ext_vector_type(2)));

// agent-scope relaxed atomic load/store = sc-flagged, bypass stale L1/L2, no fences
#define AL8(p)    __hip_atomic_load((const ulong64*)(p), __ATOMIC_RELAXED, __HIP_MEMORY_SCOPE_AGENT)
#define AS4(p, v) __hip_atomic_store((uint*)(p), (v), __ATOMIC_RELAXED, __HIP_MEMORY_SCOPE_AGENT)

// ---------------- persistent device state ----------------
// act layout: [q][b] uint4, q = kpair/4 (64), b = batch (128); uint = f16 pair (cols 2m,2m+1)
__device__ __align__(16) uint4 g_h0Q[2][64 * 128];
__device__ __align__(16) uint4 g_h1Q[2][64 * 128];
__device__ __align__(16) float g_Wcomb[4 * HID * HID];   // 0.1 * W0s @ Wfc [2048][512]
__device__ int g_cnt[512 * CPAD];                        // per-phase arrival counters

// ---------------- helpers ----------------
__device__ __forceinline__ float sigf(float x) { return 1.f / (1.f + __expf(-x)); }
__device__ __forceinline__ float tanh_fast(float x) {
  float ax = fabsf(x); float e = __expf(-2.f * ax);
  return copysignf((1.f - e) / (1.f + e), x);
}
__device__ __forceinline__ uint pack_f16(float a, float b) {
  half2v h; h.x = (_Float16)a; h.y = (_Float16)b;
  return __builtin_bit_cast(uint, h);
}
__device__ __forceinline__ float2 up2(uint u) {
  half2v h = __builtin_bit_cast(half2v, u);
  return make_float2((float)h.x, (float)h.y);
}
__device__ __forceinline__ float fdot2(uint a, uint w, float c) {
#if __has_builtin(__builtin_amdgcn_fdot2)
  return __builtin_amdgcn_fdot2(__builtin_bit_cast(half2v, a),
                                __builtin_bit_cast(half2v, w), c, false);
#else
  float2 av = up2(a), wv = up2(w);
  return fmaf(av.x, wv.x, fmaf(av.y, wv.y, c));
#endif
}
__device__ __forceinline__ void dot8(uint a, uint4 w0, uint4 w1, float* acc) {
  acc[0] = fdot2(a, w0.x, acc[0]); acc[1] = fdot2(a, w0.y, acc[1]);
  acc[2] = fdot2(a, w0.z, acc[2]); acc[3] = fdot2(a, w0.w, acc[3]);
  acc[4] = fdot2(a, w1.x, acc[4]); acc[5] = fdot2(a, w1.y, acc[5]);
  acc[6] = fdot2(a, w1.z, acc[6]); acc[7] = fdot2(a, w1.w, acc[7]);
}
// 16 uint4 act rows (64 kpairs, loaded as coherent 8B atomics) x 8 gate rows
__device__ __forceinline__ void dots16(const uint4* __restrict__ apq,
                                       const uint*  __restrict__ wb,
                                       float* __restrict__ acc) {
  const ulong64* ap = (const ulong64*)apq;
#pragma unroll 4
  for (int i = 0; i < 16; ++i) {
    ulong64 lo = AL8(ap + i * 256);
    ulong64 hi = AL8(ap + i * 256 + 1);
    const uint4* w4 = (const uint4*)(wb + 32 * i);
    dot8((uint)lo,         w4[0], w4[1], acc);
    dot8((uint)(lo >> 32), w4[2], w4[3], acc);
    dot8((uint)hi,         w4[4], w4[5], acc);
    dot8((uint)(hi >> 32), w4[6], w4[7], acc);
  }
}

// poll one counter line (all lanes same address -> 1 line request)
__device__ __forceinline__ void cnt_wait(int pid) {
  int guard = 0;
  while (__hip_atomic_load(&g_cnt[pid * CPAD], __ATOMIC_RELAXED, __HIP_MEMORY_SCOPE_AGENT) < NB) {
    __builtin_amdgcn_s_sleep(2);
    if (++guard > SPIN_MAX) break;
  }
  __builtin_amdgcn_sched_barrier(0);   // pin: no loads hoisted above the poll
}

// group wait: poller wave polls global counter, siblings spin on LDS release word
__device__ __forceinline__ void group_wait(int pid, int pw, int tid, int* rel) {
  if ((tid >> 6) == pw) {
    cnt_wait(pid);
    if ((tid & 63) == 0)
      __hip_atomic_store(&rel[pid & 1], pid, __ATOMIC_RELEASE, __HIP_MEMORY_SCOPE_WORKGROUP);
  } else {
    int guard = 0;
    while (__hip_atomic_load(&rel[pid & 1], __ATOMIC_ACQUIRE, __HIP_MEMORY_SCOPE_WORKGROUP) < pid) {
      __builtin_amdgcn_s_sleep(1);
      if (++guard > SPIN_MAX) break;
    }
    __builtin_amdgcn_sched_barrier(0);
  }
}

// ---------------- setup ----------------
__global__ void setup_kernel(float* __restrict__ out, int T) {
  int idx = blockIdx.x * blockDim.x + threadIdx.x;
  int n   = gridDim.x * blockDim.x;
  uint* z0 = (uint*)g_h0Q;
  uint* z1 = (uint*)g_h1Q;
  for (int i = idx; i < 2 * 64 * 128 * 4; i += n) { z0[i] = 0u; z1[i] = 0u; }
  for (int t = idx; t < T; t += n) out[BATCH * T * SSZ + t] = (float)t * 0.1f;
  for (int i = idx; i < 512 * CPAD; i += n) g_cnt[i] = 0;
}

// ---------------- Wcomb = 0.1 * W0s @ Wfc ----------------
__global__ void wcomb_kernel(const float* __restrict__ Wih0, const float* __restrict__ Wfc) {
  int idx = blockIdx.x * blockDim.x + threadIdx.x;
  int row = idx >> 9, k = idx & (HID - 1);
  float a = 0.f;
#pragma unroll
  for (int m = 0; m < SSZ; m++) a += Wih0[row * (XSZ + SSZ) + XSZ + m] * Wfc[m * HID + k];
  g_Wcomb[idx] = 0.1f * a;
}

// ---------------- persistent RNN kernel ----------------
__global__ __launch_bounds__(BT, 4) void persist_kernel(
    const float* __restrict__ x,    const float* __restrict__ s0,
    const float* __restrict__ Wih0, const float* __restrict__ Whh0,
    const float* __restrict__ bih0, const float* __restrict__ bhh0,
    const float* __restrict__ Wih1, const float* __restrict__ Whh1,
    const float* __restrict__ bih1, const float* __restrict__ bhh1,
    const float* __restrict__ Wfc,  const float* __restrict__ bfc,
    float* __restrict__ out, int T)
{
  __shared__ uint  lwT[4][256][8];    // [mat][kpair][row] f16 pairs: 0:W0h 1:Wcomb 2:W1a 3:W1b
  __shared__ float gbuf[8][8][128];   // [ks][row][b] partials
  __shared__ float sbase[8][128];     // x.W0x + biases
  __shared__ float c0s[2][128], c1s[2][128];
  __shared__ uint  wfcP[16][268];     // Wfc f16 pairs, padded rows
  __shared__ float b1s[8], ucs[8];
  __shared__ int   rel[2];            // LDS release words (even/odd pid)

  const int bk  = blockIdx.x;
  const int tid = threadIdx.x;
  const int ks  = tid >> 7;        // K-slice 0..7 (0-3: h0-K, 4-7: h1-K)
  const int b   = tid & 127;       // batch column
  const int q0  = (ks & 3) * 16;   // uint4-row base of this K-slice
  const int kp0 = (ks & 3) * 64;   // kpair base

  if (tid == 0) { rel[0] = -1; rel[1] = -1; }

  // ---- stage weights to LDS as f16 pairs (transposed: [kpair][row]) ----
  for (int e = tid; e < 4 * 256 * 8; e += BT) {
    int mat = e >> 11, kp = (e >> 3) & 255, r = e & 7;
    int row = (r >> 1) * HID + 2 * bk + (r & 1);
    const float* src = (mat == 0) ? &Whh0[row * HID]
                     : (mat == 1) ? &g_Wcomb[row * HID]
                     : (mat == 2) ? &Wih1[row * HID] : &Whh1[row * HID];
    lwT[mat][kp][r] = pack_f16(src[2 * kp], src[2 * kp + 1]);
  }
  for (int e = tid; e < 16 * 256; e += BT) {
    int fs_ = e >> 8, kp = e & 255;
    wfcP[fs_][kp] = pack_f16(Wfc[fs_ * HID + 2 * kp], Wfc[fs_ * HID + 2 * kp + 1]);
  }
  // ---- sbase = x.W0x + biases ----
  {
    int r = tid >> 7, bb = tid & 127;
    int row = (r >> 1) * HID + 2 * bk + (r & 1);
    float a = bih0[row] + bhh0[row];
    const float* wr = Wih0 + row * (XSZ + SSZ);
#pragma unroll 4
    for (int k = 0; k < XSZ; k++) a = fmaf(wr[k], x[bb * XSZ + k], a);
    sbase[r][bb] = a;
  }
  if (tid < 8) {
    int row = (tid >> 1) * HID + 2 * bk + (tid & 1);
    b1s[tid] = bih1[row] + bhh1[row];
    float uc = 0.f;
    const float* ws = Wih0 + row * (XSZ + SSZ) + XSZ;
#pragma unroll
    for (int m = 0; m < SSZ; m++) uc = fmaf(ws[m], bfc[m], uc);
    ucs[tid] = 0.1f * uc;
  }
  __syncthreads();

  // ---- per-batch carried state (tid<128): u = W0s.s0 - uconst ; c = 0 ----
  float u[8];
  if (tid < 128) {
#pragma unroll
    for (int r = 0; r < 8; r++) {
      int row = (r >> 1) * HID + 2 * bk + (r & 1);
      const float* ws = Wih0 + row * (XSZ + SSZ) + XSZ;
      float a = 0.f;
#pragma unroll
      for (int m = 0; m < SSZ; m++) a = fmaf(ws[m], s0[b * SSZ + m], a);
      u[r] = a - ucs[r];
    }
    c0s[0][b] = 0.f; c0s[1][b] = 0.f;
    c1s[0][b] = 0.f; c1s[1][b] = 0.f;
  }

  // ---- fc lane state (wave 15 of blocks 128..255; one batch row each) ----
  const bool fcw = (bk >= 128) && ((tid >> 6) == 15);
  const int  fb = bk - 128, lane = tid & 63, fs = lane & 15, fq = lane >> 4;
  float s_reg = 0.f, bfcj = 0.f;
  if (fcw && lane < SSZ) { s_reg = s0[fb * SSZ + lane]; bfcj = bfc[lane]; }

  auto fc_step = [&](int tt, const uint4* h1base) {
    const ulong64* hp = (const ulong64*)(h1base + fq * 16 * 128 + fb);
    const uint4*   wp = (const uint4*)&wfcP[fs][fq * 64];
    float acc = 0.f;
#pragma unroll 4
    for (int i = 0; i < 16; ++i) {
      ulong64 lo = AL8(hp + i * 256);
      ulong64 hi = AL8(hp + i * 256 + 1);
      uint4 w = wp[i];
      acc = fdot2((uint)lo,         w.x, acc);
      acc = fdot2((uint)(lo >> 32), w.y, acc);
      acc = fdot2((uint)hi,         w.z, acc);
      acc = fdot2((uint)(hi >> 32), w.w, acc);
    }
    acc += __shfl_xor(acc, 16);
    acc += __shfl_xor(acc, 32);
    if (lane < SSZ) {
      float so = acc + bfcj;
      s_reg += 0.1f * so;
      out[fb * (T * SSZ) + tt * SSZ + fs] = s_reg;
      out[BATCH * T * SSZ + T + fb * (T * SSZ) + tt * SSZ + fs] = so;
    }
  };

  int p = 0;
  for (int t = 0; t < T; ++t) {
    // ================= phase A : gates0 =================
    if (ks >= 4 && t > 0) group_wait(2 * t, 8, tid, rel);   // h1_{t-1} ready
    {
      float acc[8] = {0, 0, 0, 0, 0, 0, 0, 0};
      const uint4* actQ = (ks < 4) ? g_h0Q[p] : g_h1Q[p];
      const uint*  wb   = &lwT[(ks < 4) ? 0 : 1][kp0][0];
      dots16(actQ + q0 * 128 + b, wb, acc);
#pragma unroll
      for (int r = 0; r < 8; r++) gbuf[ks][r][b] = acc[r];
    }
    __syncthreads();
    if (tid < 128) {
      float pre[8];
#pragma unroll
      for (int r = 0; r < 8; r++) {
        float s1 = gbuf[0][r][b] + gbuf[1][r][b] + gbuf[2][r][b] + gbuf[3][r][b];
        float s2 = gbuf[4][r][b] + gbuf[5][r][b] + gbuf[6][r][b] + gbuf[7][r][b];
        u[r] += s2 + ucs[r];
        pre[r] = sbase[r][b] + s1 + u[r];
      }
      float h[2];
#pragma unroll
      for (int jj = 0; jj < 2; jj++) {
        float c = c0s[jj][b];
        c = sigf(pre[2 + jj]) * c + sigf(pre[0 + jj]) * tanh_fast(pre[4 + jj]);
        c0s[jj][b] = c;
        h[jj] = sigf(pre[6 + jj]) * tanh_fast(c);
      }
      AS4(((uint*)&g_h0Q[p ^ 1][(bk >> 2) * 128 + b]) + (bk & 3), pack_f16(h[0], h[1]));
    }
    __syncthreads();   // drains vmcnt(0): all sc-stores globally visible
    if (tid == 0)
      __hip_atomic_fetch_add(&g_cnt[(2 * t + 1) * CPAD], 1, __ATOMIC_RELAXED, __HIP_MEMORY_SCOPE_AGENT);

    // ================= phase B : gates1 =================
    if (ks < 4) group_wait(2 * t + 1, 0, tid, rel);         // h0_t ready
    {
      float acc[8] = {0, 0, 0, 0, 0, 0, 0, 0};
      const uint4* actQ = (ks < 4) ? g_h0Q[p ^ 1] : g_h1Q[p];
      const uint*  wb   = &lwT[(ks < 4) ? 2 : 3][kp0][0];
      dots16(actQ + q0 * 128 + b, wb, acc);
#pragma unroll
      for (int r = 0; r < 8; r++) gbuf[ks][r][b] = acc[r];
    }
    if (fcw && t > 0) fc_step(t - 1, g_h1Q[p]);   // fc for step t-1, in phase-B slack
    __syncthreads();
    if (tid < 128) {
      float pre[8];
#pragma unroll
      for (int r = 0; r < 8; r++) {
        float s1 = gbuf[0][r][b] + gbuf[1][r][b] + gbuf[2][r][b] + gbuf[3][r][b];
        float s2 = gbuf[4][r][b] + gbuf[5][r][b] + gbuf[6][r][b] + gbuf[7][r][b];
        pre[r] = b1s[r] + s1 + s2;
      }
      float h[2];
#pragma unroll
      for (int jj = 0; jj < 2; jj++) {
        float c = c1s[jj][b];
        c = sigf(pre[2 + jj]) * c + sigf(pre[0 + jj]) * tanh_fast(pre[4 + jj]);
        c1s[jj][b] = c;
        h[jj] = sigf(pre[6 + jj]) * tanh_fast(c);
      }
      AS4(((uint*)&g_h1Q[p ^ 1][(bk >> 2) * 128 + b]) + (bk & 3), pack_f16(h[0], h[1]));
    }
    __syncthreads();   // drains vmcnt(0)
    if (tid == 0)
      __hip_atomic_fetch_add(&g_cnt[(2 * t + 2) * CPAD], 1, __ATOMIC_RELAXED, __HIP_MEMORY_SCOPE_AGENT);
    p ^= 1;
  }

  // ---- final fc for step T-1 ----
  if (fcw) {
    cnt_wait(2 * T);
    fc_step(T - 1, g_h1Q[p]);
  }
}

extern "C" void kernel_launch(void* const* d_in, const int* in_sizes, int n_in,
                              void* d_out, int out_size, void* d_ws, size_t ws_size,
                              hipStream_t stream) {
  const float* x    = (const float*)d_in[0];
  const float* s0   = (const float*)d_in[1];
  const float* Wih0 = (const float*)d_in[2];
  const float* Whh0 = (const float*)d_in[3];
  const float* bih0 = (const float*)d_in[4];
  const float* bhh0 = (const float*)d_in[5];
  const float* Wih1 = (const float*)d_in[6];
  const float* Whh1 = (const float*)d_in[7];
  const float* bih1 = (const float*)d_in[8];
  const float* bhh1 = (const float*)d_in[9];
  const float* Wfc  = (const float*)d_in[10];
  const float* bfc  = (const float*)d_in[11];
  float* out = (float*)d_out;

  const int T = out_size / (2 * BATCH * SSZ + 1);

  setup_kernel<<<64, 256, 0, stream>>>(out, T);
  wcomb_kernel<<<(4 * HID * HID) / 256, 256, 0, stream>>>(Wih0, Wfc);
  persist_kernel<<<NB, BT, 0, stream>>>(x, s0, Wih0, Whh0, bih0, bhh0,
                                        Wih1, Whh1, bih1, bhh1, Wfc, bfc, out, T);
}

// Round 8
// 4706.990 us; speedup vs baseline: 6.3058x; 1.1621x over previous
//
#include <hip/hip_runtime.h>

#define NB    256
#define BT    1024
#define BATCH 128
#define HID   512
#define XSZ   64
#define SSZ   16
#define CPAD  32                 // ints per counter slot = 128B line
#define SPIN_MAX (1 << 17)

typedef unsigned int uint;
typedef unsigned long long ulong64;
typedef _Float16 half2v __attribute__((ext_vector_type(2)));

// agent-scope relaxed atomic load/store = sc-flagged, bypass stale L1/L2, no fences
#define AL8(p)    __hip_atomic_load((const ulong64*)(p), __ATOMIC_RELAXED, __HIP_MEMORY_SCOPE_AGENT)
#define AS4(p, v) __hip_atomic_store((uint*)(p), (v), __ATOMIC_RELAXED, __HIP_MEMORY_SCOPE_AGENT)

// ---------------- persistent device state ----------------
// act layout: [q][b] uint4, q = kpair/4 (64), b = batch (128); uint = f16 pair (cols 2m,2m+1)
__device__ __align__(16) uint4 g_h0Q[2][64 * 128];
__device__ __align__(16) uint4 g_h1Q[2][64 * 128];
__device__ __align__(16) float g_Wcomb[4 * HID * HID];   // 0.1 * W0s @ Wfc [2048][512]
__device__ int g_cnt[512 * CPAD];                        // per-phase arrival counters

// ---------------- helpers ----------------
__device__ __forceinline__ float sigf(float x) { return 1.f / (1.f + __expf(-x)); }
__device__ __forceinline__ float tanh_fast(float x) {
  float ax = fabsf(x); float e = __expf(-2.f * ax);
  return copysignf((1.f - e) / (1.f + e), x);
}
__device__ __forceinline__ uint pack_f16(float a, float b) {
  half2v h; h.x = (_Float16)a; h.y = (_Float16)b;
  return __builtin_bit_cast(uint, h);
}
__device__ __forceinline__ float2 up2(uint u) {
  half2v h = __builtin_bit_cast(half2v, u);
  return make_float2((float)h.x, (float)h.y);
}
__device__ __forceinline__ float fdot2(uint a, uint w, float c) {
#if __has_builtin(__builtin_amdgcn_fdot2)
  return __builtin_amdgcn_fdot2(__builtin_bit_cast(half2v, a),
                                __builtin_bit_cast(half2v, w), c, false);
#else
  float2 av = up2(a), wv = up2(w);
  return fmaf(av.x, wv.x, fmaf(av.y, wv.y, c));
#endif
}
__device__ __forceinline__ void dot8(uint a, uint4 w0, uint4 w1, float* acc) {
  acc[0] = fdot2(a, w0.x, acc[0]); acc[1] = fdot2(a, w0.y, acc[1]);
  acc[2] = fdot2(a, w0.z, acc[2]); acc[3] = fdot2(a, w0.w, acc[3]);
  acc[4] = fdot2(a, w1.x, acc[4]); acc[5] = fdot2(a, w1.y, acc[5]);
  acc[6] = fdot2(a, w1.z, acc[6]); acc[7] = fdot2(a, w1.w, acc[7]);
}
// 16 uint4 act rows x 8 gate rows — ALL 32 coherent loads issued first (manual MLP:
// the compiler will not hoist/batch atomic loads itself), then pure compute.
__device__ __forceinline__ void dots16(const uint4* __restrict__ apq,
                                       const uint*  __restrict__ wb,
                                       float* __restrict__ acc) {
  const ulong64* ap = (const ulong64*)apq;
  ulong64 lo[16], hi[16];
#pragma unroll
  for (int i = 0; i < 16; ++i) {
    lo[i] = AL8(ap + i * 256);
    hi[i] = AL8(ap + i * 256 + 1);
  }
#pragma unroll
  for (int i = 0; i < 16; ++i) {
    const uint4* w4 = (const uint4*)(wb + 32 * i);
    dot8((uint)lo[i],         w4[0], w4[1], acc);
    dot8((uint)(lo[i] >> 32), w4[2], w4[3], acc);
    dot8((uint)hi[i],         w4[4], w4[5], acc);
    dot8((uint)(hi[i] >> 32), w4[6], w4[7], acc);
  }
}

// poll one counter line (all lanes same address -> 1 line request)
__device__ __forceinline__ void cnt_wait(int pid) {
  int guard = 0;
  while (__hip_atomic_load(&g_cnt[pid * CPAD], __ATOMIC_RELAXED, __HIP_MEMORY_SCOPE_AGENT) < NB) {
    __builtin_amdgcn_s_sleep(2);
    if (++guard > SPIN_MAX) break;
  }
  __builtin_amdgcn_sched_barrier(0);   // pin: no loads hoisted above the poll
}

// group wait: poller wave polls global counter, siblings spin on LDS release word
__device__ __forceinline__ void group_wait(int pid, int pw, int tid, int* rel) {
  if ((tid >> 6) == pw) {
    cnt_wait(pid);
    if ((tid & 63) == 0)
      __hip_atomic_store(&rel[pid & 1], pid, __ATOMIC_RELEASE, __HIP_MEMORY_SCOPE_WORKGROUP);
  } else {
    int guard = 0;
    while (__hip_atomic_load(&rel[pid & 1], __ATOMIC_ACQUIRE, __HIP_MEMORY_SCOPE_WORKGROUP) < pid) {
      __builtin_amdgcn_s_sleep(1);
      if (++guard > SPIN_MAX) break;
    }
    __builtin_amdgcn_sched_barrier(0);
  }
}

// ---------------- setup ----------------
__global__ void setup_kernel(float* __restrict__ out, int T) {
  int idx = blockIdx.x * blockDim.x + threadIdx.x;
  int n   = gridDim.x * blockDim.x;
  uint* z0 = (uint*)g_h0Q;
  uint* z1 = (uint*)g_h1Q;
  for (int i = idx; i < 2 * 64 * 128 * 4; i += n) { z0[i] = 0u; z1[i] = 0u; }
  for (int t = idx; t < T; t += n) out[BATCH * T * SSZ + t] = (float)t * 0.1f;
  for (int i = idx; i < 512 * CPAD; i += n) g_cnt[i] = 0;
}

// ---------------- Wcomb = 0.1 * W0s @ Wfc ----------------
__global__ void wcomb_kernel(const float* __restrict__ Wih0, const float* __restrict__ Wfc) {
  int idx = blockIdx.x * blockDim.x + threadIdx.x;
  int row = idx >> 9, k = idx & (HID - 1);
  float a = 0.f;
#pragma unroll
  for (int m = 0; m < SSZ; m++) a += Wih0[row * (XSZ + SSZ) + XSZ + m] * Wfc[m * HID + k];
  g_Wcomb[idx] = 0.1f * a;
}

// ---------------- persistent RNN kernel ----------------
__global__ __launch_bounds__(BT, 4) void persist_kernel(
    const float* __restrict__ x,    const float* __restrict__ s0,
    const float* __restrict__ Wih0, const float* __restrict__ Whh0,
    const float* __restrict__ bih0, const float* __restrict__ bhh0,
    const float* __restrict__ Wih1, const float* __restrict__ Whh1,
    const float* __restrict__ bih1, const float* __restrict__ bhh1,
    const float* __restrict__ Wfc,  const float* __restrict__ bfc,
    float* __restrict__ out, int T)
{
  __shared__ uint  lwT[4][256][8];    // [mat][kpair][row] f16 pairs: 0:W0h 1:Wcomb 2:W1a 3:W1b
  __shared__ float gbuf[8][8][128];   // [ks][row][b] partials
  __shared__ float sbase[8][128];     // x.W0x + biases
  __shared__ float c0s[2][128], c1s[2][128];
  __shared__ uint  wfcP[16][268];     // Wfc f16 pairs, padded rows
  __shared__ float b1s[8], ucs[8];
  __shared__ int   rel[2];            // LDS release words (even/odd pid)

  const int bk  = blockIdx.x;
  const int tid = threadIdx.x;
  const int ks  = tid >> 7;        // K-slice 0..7 (0-3: h0-K, 4-7: h1-K)
  const int b   = tid & 127;       // batch column
  const int q0  = (ks & 3) * 16;   // uint4-row base of this K-slice
  const int kp0 = (ks & 3) * 64;   // kpair base

  if (tid == 0) { rel[0] = -1; rel[1] = -1; }

  // ---- stage weights to LDS as f16 pairs (transposed: [kpair][row]) ----
  for (int e = tid; e < 4 * 256 * 8; e += BT) {
    int mat = e >> 11, kp = (e >> 3) & 255, r = e & 7;
    int row = (r >> 1) * HID + 2 * bk + (r & 1);
    const float* src = (mat == 0) ? &Whh0[row * HID]
                     : (mat == 1) ? &g_Wcomb[row * HID]
                     : (mat == 2) ? &Wih1[row * HID] : &Whh1[row * HID];
    lwT[mat][kp][r] = pack_f16(src[2 * kp], src[2 * kp + 1]);
  }
  for (int e = tid; e < 16 * 256; e += BT) {
    int fs_ = e >> 8, kp = e & 255;
    wfcP[fs_][kp] = pack_f16(Wfc[fs_ * HID + 2 * kp], Wfc[fs_ * HID + 2 * kp + 1]);
  }
  // ---- sbase = x.W0x + biases ----
  {
    int r = tid >> 7, bb = tid & 127;
    int row = (r >> 1) * HID + 2 * bk + (r & 1);
    float a = bih0[row] + bhh0[row];
    const float* wr = Wih0 + row * (XSZ + SSZ);
#pragma unroll 4
    for (int k = 0; k < XSZ; k++) a = fmaf(wr[k], x[bb * XSZ + k], a);
    sbase[r][bb] = a;
  }
  if (tid < 8) {
    int row = (tid >> 1) * HID + 2 * bk + (tid & 1);
    b1s[tid] = bih1[row] + bhh1[row];
    float uc = 0.f;
    const float* ws = Wih0 + row * (XSZ + SSZ) + XSZ;
#pragma unroll
    for (int m = 0; m < SSZ; m++) uc = fmaf(ws[m], bfc[m], uc);
    ucs[tid] = 0.1f * uc;
  }
  __syncthreads();

  // ---- per-batch carried state (tid<128): u = W0s.s0 - uconst ; c = 0 ----
  float u[8];
  if (tid < 128) {
#pragma unroll
    for (int r = 0; r < 8; r++) {
      int row = (r >> 1) * HID + 2 * bk + (r & 1);
      const float* ws = Wih0 + row * (XSZ + SSZ) + XSZ;
      float a = 0.f;
#pragma unroll
      for (int m = 0; m < SSZ; m++) a = fmaf(ws[m], s0[b * SSZ + m], a);
      u[r] = a - ucs[r];
    }
    c0s[0][b] = 0.f; c0s[1][b] = 0.f;
    c1s[0][b] = 0.f; c1s[1][b] = 0.f;
  }

  // ---- fc lane state (wave 15 of blocks 128..255; one batch row each) ----
  const bool fcw = (bk >= 128) && ((tid >> 6) == 15);
  const int  fb = bk - 128, lane = tid & 63, fs = lane & 15, fq = lane >> 4;
  float s_reg = 0.f, bfcj = 0.f;
  if (fcw && lane < SSZ) { s_reg = s0[fb * SSZ + lane]; bfcj = bfc[lane]; }

  auto fc_step = [&](int tt, const uint4* h1base) {
    const ulong64* hp = (const ulong64*)(h1base + fq * 16 * 128 + fb);
    ulong64 lo[16], hi[16];
#pragma unroll
    for (int i = 0; i < 16; ++i) {
      lo[i] = AL8(hp + i * 256);
      hi[i] = AL8(hp + i * 256 + 1);
    }
    const uint4* wp = (const uint4*)&wfcP[fs][fq * 64];
    float acc = 0.f;
#pragma unroll
    for (int i = 0; i < 16; ++i) {
      uint4 w = wp[i];
      acc = fdot2((uint)lo[i],         w.x, acc);
      acc = fdot2((uint)(lo[i] >> 32), w.y, acc);
      acc = fdot2((uint)hi[i],         w.z, acc);
      acc = fdot2((uint)(hi[i] >> 32), w.w, acc);
    }
    acc += __shfl_xor(acc, 16);
    acc += __shfl_xor(acc, 32);
    if (lane < SSZ) {
      float so = acc + bfcj;
      s_reg += 0.1f * so;
      out[fb * (T * SSZ) + tt * SSZ + fs] = s_reg;
      out[BATCH * T * SSZ + T + fb * (T * SSZ) + tt * SSZ + fs] = so;
    }
  };

  int p = 0;
  for (int t = 0; t < T; ++t) {
    // ================= phase A : gates0 =================
    if (ks >= 4 && t > 0) group_wait(2 * t, 8, tid, rel);   // h1_{t-1} ready
    {
      float acc[8] = {0, 0, 0, 0, 0, 0, 0, 0};
      const uint4* actQ = (ks < 4) ? g_h0Q[p] : g_h1Q[p];
      const uint*  wb   = &lwT[(ks < 4) ? 0 : 1][kp0][0];
      dots16(actQ + q0 * 128 + b, wb, acc);
#pragma unroll
      for (int r = 0; r < 8; r++) gbuf[ks][r][b] = acc[r];
    }
    __syncthreads();
    if (tid < 128) {
      float pre[8];
#pragma unroll
      for (int r = 0; r < 8; r++) {
        float s1 = gbuf[0][r][b] + gbuf[1][r][b] + gbuf[2][r][b] + gbuf[3][r][b];
        float s2 = gbuf[4][r][b] + gbuf[5][r][b] + gbuf[6][r][b] + gbuf[7][r][b];
        u[r] += s2 + ucs[r];
        pre[r] = sbase[r][b] + s1 + u[r];
      }
      float h[2];
#pragma unroll
      for (int jj = 0; jj < 2; jj++) {
        float c = c0s[jj][b];
        c = sigf(pre[2 + jj]) * c + sigf(pre[0 + jj]) * tanh_fast(pre[4 + jj]);
        c0s[jj][b] = c;
        h[jj] = sigf(pre[6 + jj]) * tanh_fast(c);
      }
      AS4(((uint*)&g_h0Q[p ^ 1][(bk >> 2) * 128 + b]) + (bk & 3), pack_f16(h[0], h[1]));
    }
    __syncthreads();   // drains vmcnt(0): all sc-stores globally visible
    if (tid == 0)
      __hip_atomic_fetch_add(&g_cnt[(2 * t + 1) * CPAD], 1, __ATOMIC_RELAXED, __HIP_MEMORY_SCOPE_AGENT);

    // ================= phase B : gates1 =================
    if (ks < 4) group_wait(2 * t + 1, 0, tid, rel);         // h0_t ready
    {
      float acc[8] = {0, 0, 0, 0, 0, 0, 0, 0};
      const uint4* actQ = (ks < 4) ? g_h0Q[p ^ 1] : g_h1Q[p];
      const uint*  wb   = &lwT[(ks < 4) ? 2 : 3][kp0][0];
      dots16(actQ + q0 * 128 + b, wb, acc);
#pragma unroll
      for (int r = 0; r < 8; r++) gbuf[ks][r][b] = acc[r];
    }
    if (fcw && t > 0) fc_step(t - 1, g_h1Q[p]);   // fc for step t-1, in phase-B slack
    __syncthreads();
    if (tid < 128) {
      float pre[8];
#pragma unroll
      for (int r = 0; r < 8; r++) {
        float s1 = gbuf[0][r][b] + gbuf[1][r][b] + gbuf[2][r][b] + gbuf[3][r][b];
        float s2 = gbuf[4][r][b] + gbuf[5][r][b] + gbuf[6][r][b] + gbuf[7][r][b];
        pre[r] = b1s[r] + s1 + s2;
      }
      float h[2];
#pragma unroll
      for (int jj = 0; jj < 2; jj++) {
        float c = c1s[jj][b];
        c = sigf(pre[2 + jj]) * c + sigf(pre[0 + jj]) * tanh_fast(pre[4 + jj]);
        c1s[jj][b] = c;
        h[jj] = sigf(pre[6 + jj]) * tanh_fast(c);
      }
      AS4(((uint*)&g_h1Q[p ^ 1][(bk >> 2) * 128 + b]) + (bk & 3), pack_f16(h[0], h[1]));
    }
    __syncthreads();   // drains vmcnt(0)
    if (tid == 0)
      __hip_atomic_fetch_add(&g_cnt[(2 * t + 2) * CPAD], 1, __ATOMIC_RELAXED, __HIP_MEMORY_SCOPE_AGENT);
    p ^= 1;
  }

  // ---- final fc for step T-1 ----
  if (fcw) {
    cnt_wait(2 * T);
    fc_step(T - 1, g_h1Q[p]);
  }
}

extern "C" void kernel_launch(void* const* d_in, const int* in_sizes, int n_in,
                              void* d_out, int out_size, void* d_ws, size_t ws_size,
                              hipStream_t stream) {
  const float* x    = (const float*)d_in[0];
  const float* s0   = (const float*)d_in[1];
  const float* Wih0 = (const float*)d_in[2];
  const float* Whh0 = (const float*)d_in[3];
  const float* bih0 = (const float*)d_in[4];
  const float* bhh0 = (const float*)d_in[5];
  const float* Wih1 = (const float*)d_in[6];
  const float* Whh1 = (const float*)d_in[7];
  const float* bih1 = (const float*)d_in[8];
  const float* bhh1 = (const float*)d_in[9];
  const float* Wfc  = (const float*)d_in[10];
  const float* bfc  = (const float*)d_in[11];
  float* out = (float*)d_out;

  const int T = out_size / (2 * BATCH * SSZ + 1);

  setup_kernel<<<64, 256, 0, stream>>>(out, T);
  wcomb_kernel<<<(4 * HID * HID) / 256, 256, 0, stream>>>(Wih0, Wfc);
  persist_kernel<<<NB, BT, 0, stream>>>(x, s0, Wih0, Whh0, bih0, bhh0,
                                        Wih1, Whh1, bih1, bhh1, Wfc, bfc, out, T);
}